// Round 11
// baseline (10477.271 us; speedup 1.0000x reference)
//
#include <hip/hip_runtime.h>
#include <stdint.h>

#define B_ 64
#define T_ 2048
#define F_ 128
#define H_ 256
#define TC_ 1022

typedef __bf16 bf16x8 __attribute__((ext_vector_type(8)));
typedef float f32x4 __attribute__((ext_vector_type(4)));
typedef uint u32x4 __attribute__((ext_vector_type(4)));
typedef unsigned long long u64;

__device__ __forceinline__ ushort f2bf(float f) {
    uint32_t u = __builtin_bit_cast(uint32_t, f);
    u += 0x7FFFu + ((u >> 16) & 1u);
    return (ushort)(u >> 16);
}
__device__ __forceinline__ float sigmoidf_(float x) {
    return __builtin_amdgcn_rcpf(1.f + __expf(-x));
}
__device__ __forceinline__ float tanhf_(float x) {
    x = fminf(15.f, fmaxf(-15.f, x));
    float e = __expf(2.f * x);
    return 1.f - 2.f * __builtin_amdgcn_rcpf(e + 1.f);
}

// ---- Kernel 1: sum of squares over T for F.normalize(dim=1) ----
__global__ __launch_bounds__(128) void k_sqsum(const float* __restrict__ in,
                                               float* __restrict__ sq) {
    int b = blockIdx.x >> 4, tq = blockIdx.x & 15, f = threadIdx.x;
    const float* p = in + ((size_t)b * T_ + (size_t)tq * 128) * F_ + f;
    float acc = 0.f;
#pragma unroll 8
    for (int t = 0; t < 128; ++t) { float v = p[(size_t)t * F_]; acc += v * v; }
    atomicAdd(&sq[b * F_ + f], acc);
}

// ---- Kernel 2: weight repack to bf16 block-row order; bias combine ----
// wbf[g2][m][k]: g2 = unit>>2 (0..63), m = uu*4+gate, k: [0,64)=w_ih, [64,320)=w_hh
__global__ __launch_bounds__(256) void k_prep(const float* __restrict__ wih, const float* __restrict__ whh,
                                              const float* __restrict__ bih, const float* __restrict__ bhh,
                                              ushort* __restrict__ wbf, float* __restrict__ bias) {
    int e = blockIdx.x * 256 + threadIdx.x;
    if (e < 64 * 16 * 320) {
        int g = e / 5120, m = (e / 320) & 15, k = e % 320;
        int j = (m & 3) * 256 + g * 4 + (m >> 2);  // gate*256 + unit
        float v = (k < 64) ? wih[j * 64 + k] : whh[j * 256 + (k - 64)];
        wbf[e] = f2bf(v);
    }
    if (e < 1024) bias[e] = bih[e] + bhh[e];
}

// ---- Kernel 3: fused normalize + conv1d(K=5,S=2) + bias + relu -> li bf16 [tc][b][72pad] ----
__global__ __launch_bounds__(256) void k_conv(const float* __restrict__ in, const float* __restrict__ cw,
                                              const float* __restrict__ cb, const float* __restrict__ sq,
                                              ushort* __restrict__ li) {
    __shared__ float rn[128];
    __shared__ __align__(16) float xs[67 * 129];
    __shared__ __align__(16) float wl[80 * 68];
    int b = blockIdx.x >> 5, tile = blockIdx.x & 31;
    int tc0 = tile * 32;
    int tid = threadIdx.x;
    if (tid < 128) { float ss = sq[b * 128 + tid]; rn[tid] = 1.f / fmaxf(sqrtf(ss), 1e-12f); }
    __syncthreads();
    const float* ip = in + ((size_t)b * T_ + (size_t)(2 * tc0)) * F_;
    for (int i = tid; i < 67 * 128; i += 256) {
        int r = i >> 7, f = i & 127;
        int t = 2 * tc0 + r;
        xs[r * 129 + f] = (t < T_) ? ip[(size_t)r * F_ + f] * rn[f] : 0.f;
    }
    int cg = tid & 15, tcg = tid >> 4;
    float a00 = 0, a01 = 0, a10 = 0, a11 = 0, a20 = 0, a21 = 0, a30 = 0, a31 = 0;
    for (int fc = 0; fc < 8; ++fc) {
        __syncthreads();
        for (int i = tid; i < 64 * 80; i += 256) {
            int c = i / 80, j = i - c * 80;
            wl[j * 68 + c] = cw[c * 640 + fc * 80 + j];
        }
        __syncthreads();
#pragma unroll
        for (int fi = 0; fi < 16; ++fi) {
#pragma unroll
            for (int k = 0; k < 5; ++k) {
                const float4 w4 = *(const float4*)&wl[(fi * 5 + k) * 68 + cg * 4];
                float x0 = xs[(4 * tcg + k) * 129 + fc * 16 + fi];
                float x1 = xs[(4 * tcg + 2 + k) * 129 + fc * 16 + fi];
                a00 += w4.x * x0; a01 += w4.x * x1;
                a10 += w4.y * x0; a11 += w4.y * x1;
                a20 += w4.z * x0; a21 += w4.z * x1;
                a30 += w4.w * x0; a31 += w4.w * x1;
            }
        }
    }
    float bc0 = cb[cg * 4 + 0], bc1 = cb[cg * 4 + 1], bc2 = cb[cg * 4 + 2], bc3 = cb[cg * 4 + 3];
#pragma unroll
    for (int tt = 0; tt < 2; ++tt) {
        int tc = tc0 + tcg * 2 + tt;
        if (tc < TC_) {
            float v0 = fmaxf((tt ? a01 : a00) + bc0, 0.f);
            float v1 = fmaxf((tt ? a11 : a10) + bc1, 0.f);
            float v2 = fmaxf((tt ? a21 : a20) + bc2, 0.f);
            float v3 = fmaxf((tt ? a31 : a30) + bc3, 0.f);
            uint2 pk;
            pk.x = (uint32_t)f2bf(v0) | ((uint32_t)f2bf(v1) << 16);
            pk.y = (uint32_t)f2bf(v2) | ((uint32_t)f2bf(v3) << 16);
            *reinterpret_cast<uint2*>(&li[((size_t)tc * 64 + b) * 72 + cg * 4]) = pk;
        }
    }
}

// ---- Kernel 3b: gx precompute — gx[t][b][1024] = bf16(W_ih @ x_t + b_ih + b_hh).
// Embarrassingly parallel GEMM (M=1024, K=64 per token). Removes W_ih (128KB) and the
// x-MFMAs from the scan loop. bf16 storage is accuracy-safe: gx is the SMALL x-part only
// (|gx| ~ 0.03-0.1 after L2-normalization), abs err ~3e-4 on O(1) gates.
// Layout matches scan consumption: row = g2*16 + quad*4 + reg (m89 C mapping), so the
// scan's lane reads its 4 gates as one 8B bf16x4.
__global__ __launch_bounds__(256, 2) void k_gx(const ushort* __restrict__ li,
                                               const ushort* __restrict__ wbf,
                                               const float* __restrict__ bias,
                                               ushort* __restrict__ gx) {
    int t = blockIdx.x >> 2, bq = blockIdx.x & 3;
    int tid = threadIdx.x;
    int lane = tid & 63, w = tid >> 6, l16 = lane & 15, quad = lane >> 4;
    int b = bq * 16 + l16;
    const ushort* xp = li + ((size_t)t * 64 + b) * 72 + quad * 8;
    bf16x8 x0 = *(const bf16x8*)xp;
    bf16x8 x1 = *(const bf16x8*)(xp + 32);
    ushort* gdst = gx + ((size_t)t * 64 + b) * 1024 + w * 256 + quad * 4;
#pragma unroll
    for (int j = 0; j < 16; ++j) {
        int g2 = w * 16 + j;
        const ushort* wp = wbf + ((size_t)(g2 * 16 + l16)) * 320 + quad * 8;
        bf16x8 a0 = *(const bf16x8*)wp;
        bf16x8 a1 = *(const bf16x8*)(wp + 32);
        f32x4 A = {0.f, 0.f, 0.f, 0.f};
        A = __builtin_amdgcn_mfma_f32_16x16x32_bf16(a0, x0, A, 0, 0, 0);
        A = __builtin_amdgcn_mfma_f32_16x16x32_bf16(a1, x1, A, 0, 0, 0);
        int u = g2 * 4 + quad;
        uint2 pk;
        pk.x = (uint)f2bf(A[0] + bias[u]) | ((uint)f2bf(A[1] + bias[256 + u]) << 16);
        pk.y = (uint)f2bf(A[2] + bias[512 + u]) | ((uint)f2bf(A[3] + bias[768 + u]) << 16);
        *(uint2*)(gdst + j * 16) = pk;
    }
}

// ---- Kernel 4: SINGLE-CU COMMUNICATION-FREE LSTM scan.
// R0-R10 ledger: ANY cross-CU rendezvous costs ~5-6k cy/step (11 protocol/placement
// variants, all flat). Fix: eliminate the exchange. Block p (4 blocks total) owns
// batches [16p,16p+16) end-to-end; h lives in block-local LDS; zero inter-block traffic.
// Capacity (the R9 failure, corrected): 4 waves x 512 VGPR (launch_bounds(256,1), 1
// wave/SIMD) = 2048 VGPR file. W_hh = 512 frags (16x16x32 A-tiles): 91/wave in regs
// (364 VGPR: tiles j<11 keep K-frags s0-5, j>=11 keep s0-4) + 148 frags in LDS (148KB,
// XOR-swizzled chunks, ~2-way = free). W_ih is gone (gx precomputed). Hs = 8.4KB.
// Per-step: 128 MFMAs/wave (16 tiles x 8 K-frags) + ~45 ds_reads + trans epilogue.
__global__ __launch_bounds__(256, 1) void k_scan2(const ushort* __restrict__ gx,
                                                  const ushort* __restrict__ wbf,
                                                  float* __restrict__ hfin) {
    __shared__ __align__(16) ushort wlds[148 * 512];  // 151552 B: 148 frag-slots x 1KB
    __shared__ __align__(16) ushort Hs[16 * 264];     // 8448 B: h [b:16][256+8 pad]
    int p = blockIdx.x;
    int tid = threadIdx.x;
    int lane = tid & 63, w = tid >> 6, l16 = lane & 15, quad = lane >> 4;
    int bb = p * 16 + l16;
    // ---- cooperative LDS weight fill: slot(w,j,s): j<11 -> {s6,s7}; j>=11 -> {s5,s6,s7}.
    // chunk c (16B) of row stored at c^((row>>1)&3) -> wave read is ~2-way (free, m136).
    for (int i = tid; i < 148 * 64; i += 256) {
        int slot = i >> 6, ch = i & 63;
        int row = ch >> 2, c = ch & 3, cp = c ^ ((row >> 1) & 3);
        int wv = slot / 37, sl = slot - wv * 37;
        int j, s;
        if (sl < 22) { j = sl >> 1; s = 6 + (sl & 1); }
        else { int r2 = sl - 22; j = 11 + r2 / 3; s = 5 + r2 % 3; }
        int g2 = wv * 16 + j;
        const ushort* src = wbf + ((size_t)(g2 * 16 + row)) * 320 + (s + 2) * 32 + c * 8;
        *(uint4*)&wlds[slot * 512 + row * 32 + cp * 8] = *(const uint4*)src;
    }
    // ---- stationary reg frags (all indices literal after unroll) ----
    bf16x8 af[16][6];
#pragma unroll
    for (int j = 0; j < 16; ++j) {
        const ushort* wp = wbf + ((size_t)((w * 16 + j) * 16 + l16)) * 320 + quad * 8;
#pragma unroll
        for (int s = 0; s < 6; ++s)
            if (s < ((j < 11) ? 6 : 5)) af[j][s] = *(const bf16x8*)(wp + (s + 2) * 32);
    }
    float cs[16];
#pragma unroll
    for (int j = 0; j < 16; ++j) cs[j] = 0.f;
    __syncthreads();  // wlds fill complete
#define SLOT_(J, S) (w * 37 + ((J) < 11 ? (J) * 2 + ((S) - 6) : 22 + ((J) - 11) * 3 + ((S) - 5)))
#define RDW_(J, S) (*(const bf16x8*)&wlds[SLOT_(J, S) * 512 + l16 * 32 + ((quad ^ ((l16 >> 1) & 3)) * 8)])
    const ushort* gxb = gx + (size_t)bb * 1024 + w * 256 + quad * 4;
#pragma unroll 1
    for (int t = 0; t < TC_; ++t) {
        const ushort* gxr = gxb + (size_t)t * 65536;
        // gx loads half 1 (epilogue j=0..7): issued at step top, used ~1500cy later.
        uint2 gq0[8];
#pragma unroll
        for (int j = 0; j < 8; ++j) gq0[j] = *(const uint2*)(gxr + j * 16);
        f32x4 A[16];
#pragma unroll
        for (int j = 0; j < 16; ++j) A[j] = (f32x4){0.f, 0.f, 0.f, 0.f};
        if (t > 0) {
            // K-frags s=0..4: registers for all tiles.
#pragma unroll
            for (int s = 0; s < 5; ++s) {
                bf16x8 bh = *(const bf16x8*)((const char*)Hs + l16 * 528 + s * 64 + quad * 16);
#pragma unroll
                for (int j = 0; j < 16; ++j)
                    A[j] = __builtin_amdgcn_mfma_f32_16x16x32_bf16(af[j][s], bh, A[j], 0, 0, 0);
            }
            // s=5: j<11 reg, j>=11 LDS.
            {
                bf16x8 bh = *(const bf16x8*)((const char*)Hs + l16 * 528 + 5 * 64 + quad * 16);
#pragma unroll
                for (int j = 0; j < 11; ++j)
                    A[j] = __builtin_amdgcn_mfma_f32_16x16x32_bf16(af[j][5], bh, A[j], 0, 0, 0);
#pragma unroll
                for (int j = 11; j < 16; ++j) {
                    bf16x8 a = RDW_(j, 5);
                    A[j] = __builtin_amdgcn_mfma_f32_16x16x32_bf16(a, bh, A[j], 0, 0, 0);
                }
            }
            // s=6,7: all tiles from LDS.
#pragma unroll
            for (int s = 6; s < 8; ++s) {
                bf16x8 bh = *(const bf16x8*)((const char*)Hs + l16 * 528 + s * 64 + quad * 16);
#pragma unroll
                for (int j = 0; j < 16; ++j) {
                    bf16x8 a = RDW_(j, s);
                    A[j] = __builtin_amdgcn_mfma_f32_16x16x32_bf16(a, bh, A[j], 0, 0, 0);
                }
            }
        }
        // gx loads half 2 (after MFMA phase to cap register pressure; ~400cy to use).
        uint2 gq1[8];
#pragma unroll
        for (int j = 0; j < 8; ++j) gq1[j] = *(const uint2*)(gxr + 128 + j * 16);
        __syncthreads();  // barrier A: all Hs reads of h(t-1) complete before overwrite
        bool lastt = (t == TC_ - 1);
#pragma unroll
        for (int j = 0; j < 16; ++j) {
            uint2 g = (j < 8) ? gq0[j] : gq1[j - 8];  // literal select
            float x0 = __builtin_bit_cast(float, g.x << 16);
            float x1 = __builtin_bit_cast(float, g.x & 0xFFFF0000u);
            float x2 = __builtin_bit_cast(float, g.y << 16);
            float x3 = __builtin_bit_cast(float, g.y & 0xFFFF0000u);
            float gi = A[j][0] + x0, gf = A[j][1] + x1;
            float gg = A[j][2] + x2, go = A[j][3] + x3;
            float ii = sigmoidf_(gi), ff = sigmoidf_(gf), gv = tanhf_(gg), oo = sigmoidf_(go);
            cs[j] = ff * cs[j] + ii * gv;
            float hv = oo * tanhf_(cs[j]);
            int u = w * 64 + j * 4 + quad;
            if (lastt) {
                hfin[u * 64 + bb] = hv;
            } else {
                ushort hb = f2bf(hv);
                uint pr = ((uint)hb) | ((uint)__shfl((int)hb, (lane + 16) & 63) << 16);
                if ((quad & 1) == 0)
                    *(uint*)((char*)Hs + l16 * 528 + u * 2) = pr;  // units u, u+1
            }
        }
        __syncthreads();  // barrier B: h(t) writes visible before next step's reads
    }
#undef SLOT_
#undef RDW_
}

// ---- Kernel 4-FALLBACK (R8-proven, 2.41ms): used when ws_size can't hold gx. ----
__global__ __launch_bounds__(512) void k_scan(const ushort* __restrict__ li,
                                              const ushort* __restrict__ wbf,
                                              const float* __restrict__ bias,
                                              u64* __restrict__ hbuf,
                                              float* __restrict__ hfin) {
    __shared__ __align__(16) ushort Hs[2][16 * 264];
    int p = blockIdx.x & 7, q = blockIdx.x >> 3;
    if (p >= 4) return;
    int tid = threadIdx.x;
    int lane = tid & 63, wave = tid >> 6, l16 = lane & 15, quad = lane >> 4;
    int bb = p * 16 + l16;
    int g2a = q * 16 + 2 * wave, g2b = g2a + 1;
    int u0 = g2a * 4 + quad, u1 = g2b * 4 + quad;
    int pc = 32 * q + 4 * wave + (quad >> 1);
    bf16x8 af0[10], af1[10];
    const ushort* wp0 = wbf + ((size_t)(g2a * 16 + l16)) * 320 + quad * 8;
    const ushort* wp1 = wbf + ((size_t)(g2b * 16 + l16)) * 320 + quad * 8;
#pragma unroll
    for (int s = 0; s < 10; ++s) { af0[s] = *(const bf16x8*)(wp0 + s * 32);
                                   af1[s] = *(const bf16x8*)(wp1 + s * 32); }
    float bi0 = bias[u0], bf0 = bias[256 + u0], bg0 = bias[512 + u0], bo0 = bias[768 + u0];
    float bi1 = bias[u1], bf1 = bias[256 + u1], bg1 = bias[512 + u1], bo1 = bias[768 + u1];
    float cs0 = 0.f, cs1 = 0.f;
    bool broken = false;
    const ushort* xpp = li + ((size_t)0 * 64 + bb) * 72 + quad * 8;
    bf16x8 x0 = *(const bf16x8*)xpp;
    bf16x8 x1 = *(const bf16x8*)(xpp + 32);
#pragma unroll 1
    for (int t = 0; t < TC_; ++t) {
        f32x4 A0 = {0.f, 0.f, 0.f, 0.f}, A1 = {0.f, 0.f, 0.f, 0.f};
        A0 = __builtin_amdgcn_mfma_f32_16x16x32_bf16(af0[0], x0, A0, 0, 0, 0);
        A1 = __builtin_amdgcn_mfma_f32_16x16x32_bf16(af1[0], x0, A1, 0, 0, 0);
        A0 = __builtin_amdgcn_mfma_f32_16x16x32_bf16(af0[1], x1, A0, 0, 0, 0);
        A1 = __builtin_amdgcn_mfma_f32_16x16x32_bf16(af1[1], x1, A1, 0, 0, 0);
        char* hb = (char*)Hs + (size_t)(t & 1) * (16 * 264 * 2);
        if (t > 0) {
            uint tg = (uint)(t - 1);
            const u64* src = hbuf + ((size_t)((t - 1) & 1) << 13) + p * 2048 + tid * 4;
            u64 vv0, vv1, vv2, vv3;
            bool got = false;
            if (!broken) {
                u32x4 pa, pb;
                bool ok;
                int guard = 0;
                do {
                    asm volatile(
                        "global_load_dwordx4 %0, %2, off sc0\n\t"
                        "global_load_dwordx4 %1, %2, off offset:16 sc0\n\t"
                        "s_waitcnt vmcnt(0)"
                        : "=&v"(pa), "=&v"(pb) : "v"(src) : "memory");
                    uint m = ((pa.x >> 16) ^ tg) | ((pa.y >> 16) ^ tg)
                           | ((pa.z >> 16) ^ tg) | ((pa.w >> 16) ^ tg)
                           | ((pb.x >> 16) ^ tg) | ((pb.y >> 16) ^ tg)
                           | ((pb.z >> 16) ^ tg) | ((pb.w >> 16) ^ tg);
                    ok = (m == 0);
                } while (!__all(ok) && ++guard < 1024);
                got = __all(ok);
                if (got) {
                    vv0 = ((u64)pa.y << 32) | pa.x;
                    vv1 = ((u64)pa.w << 32) | pa.z;
                    vv2 = ((u64)pb.y << 32) | pb.x;
                    vv3 = ((u64)pb.w << 32) | pb.z;
                } else broken = true;
            }
            if (!got) {
                u64 w0, w1, w2, w3;
                bool ok;
                int guard = 0;
                do {
                    w0 = __hip_atomic_load(src + 0, __ATOMIC_RELAXED, __HIP_MEMORY_SCOPE_AGENT);
                    w1 = __hip_atomic_load(src + 1, __ATOMIC_RELAXED, __HIP_MEMORY_SCOPE_AGENT);
                    w2 = __hip_atomic_load(src + 2, __ATOMIC_RELAXED, __HIP_MEMORY_SCOPE_AGENT);
                    w3 = __hip_atomic_load(src + 3, __ATOMIC_RELAXED, __HIP_MEMORY_SCOPE_AGENT);
                    uint m = (((uint)(w0 >> 16) & 0xFFFFu) ^ tg) | (((uint)(w0 >> 48)) ^ tg);
                    m |= (((uint)(w1 >> 16) & 0xFFFFu) ^ tg) | (((uint)(w1 >> 48)) ^ tg);
                    m |= (((uint)(w2 >> 16) & 0xFFFFu) ^ tg) | (((uint)(w2 >> 48)) ^ tg);
                    m |= (((uint)(w3 >> 16) & 0xFFFFu) ^ tg) | (((uint)(w3 >> 48)) ^ tg);
                    ok = (m == 0);
                } while (!__all(ok) && ++guard < (1 << 14));
                vv0 = w0; vv1 = w1; vv2 = w2; vv3 = w3;
            }
            {
                int b = tid >> 5, c0 = (tid * 4) & 127;
                uint4 wv;
                wv.x = ((uint)vv0 & 0xFFFFu) | (((uint)(vv0 >> 32) & 0xFFFFu) << 16);
                wv.y = ((uint)vv1 & 0xFFFFu) | (((uint)(vv1 >> 32) & 0xFFFFu) << 16);
                wv.z = ((uint)vv2 & 0xFFFFu) | (((uint)(vv2 >> 32) & 0xFFFFu) << 16);
                wv.w = ((uint)vv3 & 0xFFFFu) | (((uint)(vv3 >> 32) & 0xFFFFu) << 16);
                *(uint4*)(hb + b * 528 + c0 * 4) = wv;
            }
            __syncthreads();
#pragma unroll
            for (int s = 0; s < 8; ++s) {
                bf16x8 bh = *(const bf16x8*)(hb + l16 * 528 + s * 64 + quad * 16);
                A0 = __builtin_amdgcn_mfma_f32_16x16x32_bf16(af0[2 + s], bh, A0, 0, 0, 0);
                A1 = __builtin_amdgcn_mfma_f32_16x16x32_bf16(af1[2 + s], bh, A1, 0, 0, 0);
            }
        }
        float hv0, hv1;
        {
            float gi = A0[0] + bi0, gf = A0[1] + bf0, gg = A0[2] + bg0, go = A0[3] + bo0;
            float ii = sigmoidf_(gi), ff = sigmoidf_(gf), g2 = tanhf_(gg), oo = sigmoidf_(go);
            cs0 = ff * cs0 + ii * g2;
            hv0 = oo * tanhf_(cs0);
        }
        {
            float gi = A1[0] + bi1, gf = A1[1] + bf1, gg = A1[2] + bg1, go = A1[3] + bo1;
            float ii = sigmoidf_(gi), ff = sigmoidf_(gf), g2 = tanhf_(gg), oo = sigmoidf_(go);
            cs1 = ff * cs1 + ii * g2;
            hv1 = oo * tanhf_(cs1);
        }
        if (t == TC_ - 1) {
            hfin[u0 * 64 + bb] = hv0;
            hfin[u1 * 64 + bb] = hv1;
        } else {
            ushort h0 = f2bf(hv0), h1 = f2bf(hv1);
            uint pr0 = ((uint)h0 & 0xFFFFu) | ((uint)__shfl((int)h0, (lane + 16) & 63) << 16);
            uint pr1 = ((uint)h1 & 0xFFFFu) | ((uint)__shfl((int)h1, (lane + 16) & 63) << 16);
            if ((quad & 1) == 0) {
                uint tg2 = ((uint)t) << 16;
                u64 w0 = (u64)((pr0 & 0xFFFFu) | tg2) | ((u64)((pr0 >> 16) | tg2) << 32);
                u64 w1 = (u64)((pr1 & 0xFFFFu) | tg2) | ((u64)((pr1 >> 16) | tg2) << 32);
                u64* dst = hbuf + ((size_t)(t & 1) << 13) + p * 2048 + l16 * 128;
                __hip_atomic_store(dst + pc, w0, __ATOMIC_RELAXED, __HIP_MEMORY_SCOPE_AGENT);
                __hip_atomic_store(dst + pc + 2, w1, __ATOMIC_RELAXED, __HIP_MEMORY_SCOPE_AGENT);
            }
        }
        int tn = (t + 1 < TC_) ? t + 1 : t;
        const ushort* xpn = li + ((size_t)tn * 64 + bb) * 72 + quad * 8;
        x0 = *(const bf16x8*)xpn;
        x1 = *(const bf16x8*)(xpn + 32);
    }
}

// ---- Kernel 5: out[b][o] = h_final[:,b] . lin_w[o,:] + lin_b[o] ----
__global__ __launch_bounds__(64) void k_fin(const float* __restrict__ hfin, const float* __restrict__ lw,
                                            const float* __restrict__ lb, float* __restrict__ out) {
    int o = blockIdx.x, b = threadIdx.x;
    float acc = lb[o];
    const float* wp = lw + o * 256;
#pragma unroll 4
    for (int u2 = 0; u2 < 256; ++u2) acc += hfin[u2 * 64 + b] * wp[u2];
    out[b * 10 + o] = acc;
}

extern "C" void kernel_launch(void* const* d_in, const int* in_sizes, int n_in,
                              void* d_out, int out_size, void* d_ws, size_t ws_size,
                              hipStream_t stream) {
    const float* in  = (const float*)d_in[0];
    // d_in[1] ("r") unused
    const float* cw  = (const float*)d_in[2];
    const float* cb  = (const float*)d_in[3];
    const float* wih = (const float*)d_in[4];
    const float* whh = (const float*)d_in[5];
    const float* bih = (const float*)d_in[6];
    const float* bhh = (const float*)d_in[7];
    const float* lw  = (const float*)d_in[8];
    const float* lb  = (const float*)d_in[9];
    float* out = (float*)d_out;

    char* ws = (char*)d_ws;
    float*  sq   = (float*)(ws + 0);          // 32768 B
    u64*    hbuf = (u64*)(ws + 32768);        // 131072 B (fallback exchange buffer)
    float*  bias = (float*)(ws + 163840);     // 4096 B
    float*  hfin = (float*)(ws + 167936);     // 65536 B  [u][b] fp32
    ushort* wbf  = (ushort*)(ws + 233472);    // 655360 B [g2][16][320] bf16
    ushort* li   = (ushort*)(ws + 888832);    // 9418752 B [tc][b][72] bf16
    ushort* gx   = (ushort*)(ws + 10307584);  // 133955584 B [tc][b][1024] bf16
    const size_t WS_NEED = 10307584ull + 133955584ull;  // 144,263,168

    hipMemsetAsync(sq, 0, 32768, stream);

    k_sqsum<<<1024, 128, 0, stream>>>(in, sq);
    k_prep<<<1280, 256, 0, stream>>>(wih, whh, bih, bhh, wbf, bias);
    k_conv<<<2048, 256, 0, stream>>>(in, cw, cb, sq, li);
    if (ws_size >= WS_NEED) {
        // Communication-free path: precompute gx, then 4 independent single-CU scans.
        k_gx<<<TC_ * 4, 256, 0, stream>>>(li, wbf, bias, gx);
        k_scan2<<<4, 256, 0, stream>>>(gx, wbf, hfin);
    } else {
        // Fallback: R8-proven pod exchange (2.41 ms).
        hipMemsetAsync(hbuf, 0xFF, 131072, stream);
        k_scan<<<32, 512, 0, stream>>>(li, wbf, bias, hbuf, hfin);
    }
    k_fin<<<10, 64, 0, stream>>>(hfin, lw, lb, out);
}

// Round 12
// 6813.999 us; speedup vs baseline: 1.5376x; 1.5376x over previous
//
#include <hip/hip_runtime.h>
#include <stdint.h>

#define B_ 64
#define T_ 2048
#define F_ 128
#define H_ 256
#define TC_ 1022

typedef __bf16 bf16x8 __attribute__((ext_vector_type(8)));
typedef float f32x4 __attribute__((ext_vector_type(4)));
typedef uint u32x4 __attribute__((ext_vector_type(4)));
typedef unsigned long long u64;

__device__ __forceinline__ ushort f2bf(float f) {
    uint32_t u = __builtin_bit_cast(uint32_t, f);
    u += 0x7FFFu + ((u >> 16) & 1u);
    return (ushort)(u >> 16);
}
__device__ __forceinline__ float sigmoidf_(float x) {
    return __builtin_amdgcn_rcpf(1.f + __expf(-x));
}
__device__ __forceinline__ float tanhf_(float x) {
    x = fminf(15.f, fmaxf(-15.f, x));
    float e = __expf(2.f * x);
    return 1.f - 2.f * __builtin_amdgcn_rcpf(e + 1.f);
}

// ---- Kernel 1: sum of squares over T for F.normalize(dim=1) ----
__global__ __launch_bounds__(128) void k_sqsum(const float* __restrict__ in,
                                               float* __restrict__ sq) {
    int b = blockIdx.x >> 4, tq = blockIdx.x & 15, f = threadIdx.x;
    const float* p = in + ((size_t)b * T_ + (size_t)tq * 128) * F_ + f;
    float acc = 0.f;
#pragma unroll 8
    for (int t = 0; t < 128; ++t) { float v = p[(size_t)t * F_]; acc += v * v; }
    atomicAdd(&sq[b * F_ + f], acc);
}

// ---- Kernel 2: weight repack to bf16 block-row order; bias combine ----
// wbf[g2][m][k]: g2 = unit>>2 (0..63), m = uu*4+gate, k: [0,64)=w_ih, [64,320)=w_hh
__global__ __launch_bounds__(256) void k_prep(const float* __restrict__ wih, const float* __restrict__ whh,
                                              const float* __restrict__ bih, const float* __restrict__ bhh,
                                              ushort* __restrict__ wbf, float* __restrict__ bias) {
    int e = blockIdx.x * 256 + threadIdx.x;
    if (e < 64 * 16 * 320) {
        int g = e / 5120, m = (e / 320) & 15, k = e % 320;
        int j = (m & 3) * 256 + g * 4 + (m >> 2);  // gate*256 + unit
        float v = (k < 64) ? wih[j * 64 + k] : whh[j * 256 + (k - 64)];
        wbf[e] = f2bf(v);
    }
    if (e < 1024) bias[e] = bih[e] + bhh[e];
}

// ---- Kernel 3: fused normalize + conv1d(K=5,S=2) + bias + relu -> li bf16 [tc][b][72pad] ----
__global__ __launch_bounds__(256) void k_conv(const float* __restrict__ in, const float* __restrict__ cw,
                                              const float* __restrict__ cb, const float* __restrict__ sq,
                                              ushort* __restrict__ li) {
    __shared__ float rn[128];
    __shared__ __align__(16) float xs[67 * 129];
    __shared__ __align__(16) float wl[80 * 68];
    int b = blockIdx.x >> 5, tile = blockIdx.x & 31;
    int tc0 = tile * 32;
    int tid = threadIdx.x;
    if (tid < 128) { float ss = sq[b * 128 + tid]; rn[tid] = 1.f / fmaxf(sqrtf(ss), 1e-12f); }
    __syncthreads();
    const float* ip = in + ((size_t)b * T_ + (size_t)(2 * tc0)) * F_;
    for (int i = tid; i < 67 * 128; i += 256) {
        int r = i >> 7, f = i & 127;
        int t = 2 * tc0 + r;
        xs[r * 129 + f] = (t < T_) ? ip[(size_t)r * F_ + f] * rn[f] : 0.f;
    }
    int cg = tid & 15, tcg = tid >> 4;
    float a00 = 0, a01 = 0, a10 = 0, a11 = 0, a20 = 0, a21 = 0, a30 = 0, a31 = 0;
    for (int fc = 0; fc < 8; ++fc) {
        __syncthreads();
        for (int i = tid; i < 64 * 80; i += 256) {
            int c = i / 80, j = i - c * 80;
            wl[j * 68 + c] = cw[c * 640 + fc * 80 + j];
        }
        __syncthreads();
#pragma unroll
        for (int fi = 0; fi < 16; ++fi) {
#pragma unroll
            for (int k = 0; k < 5; ++k) {
                const float4 w4 = *(const float4*)&wl[(fi * 5 + k) * 68 + cg * 4];
                float x0 = xs[(4 * tcg + k) * 129 + fc * 16 + fi];
                float x1 = xs[(4 * tcg + 2 + k) * 129 + fc * 16 + fi];
                a00 += w4.x * x0; a01 += w4.x * x1;
                a10 += w4.y * x0; a11 += w4.y * x1;
                a20 += w4.z * x0; a21 += w4.z * x1;
                a30 += w4.w * x0; a31 += w4.w * x1;
            }
        }
    }
    float bc0 = cb[cg * 4 + 0], bc1 = cb[cg * 4 + 1], bc2 = cb[cg * 4 + 2], bc3 = cb[cg * 4 + 3];
#pragma unroll
    for (int tt = 0; tt < 2; ++tt) {
        int tc = tc0 + tcg * 2 + tt;
        if (tc < TC_) {
            float v0 = fmaxf((tt ? a01 : a00) + bc0, 0.f);
            float v1 = fmaxf((tt ? a11 : a10) + bc1, 0.f);
            float v2 = fmaxf((tt ? a21 : a20) + bc2, 0.f);
            float v3 = fmaxf((tt ? a31 : a30) + bc3, 0.f);
            uint2 pk;
            pk.x = (uint32_t)f2bf(v0) | ((uint32_t)f2bf(v1) << 16);
            pk.y = (uint32_t)f2bf(v2) | ((uint32_t)f2bf(v3) << 16);
            *reinterpret_cast<uint2*>(&li[((size_t)tc * 64 + b) * 72 + cg * 4]) = pk;
        }
    }
}

// ---- Kernel 3b: gx precompute — gx[t][b][1024] = bf16(W_ih @ x_t + b_ih + b_hh).
// UNCHANGED from R11 (correctness-proven, absmax 2.4e-4). gx[t][b][4u..4u+3] =
// (i,f,g,o) of unit u — mapping is consumer-agnostic.
__global__ __launch_bounds__(256, 2) void k_gx(const ushort* __restrict__ li,
                                               const ushort* __restrict__ wbf,
                                               const float* __restrict__ bias,
                                               ushort* __restrict__ gx) {
    int t = blockIdx.x >> 2, bq = blockIdx.x & 3;
    int tid = threadIdx.x;
    int lane = tid & 63, w = tid >> 6, l16 = lane & 15, quad = lane >> 4;
    int b = bq * 16 + l16;
    const ushort* xp = li + ((size_t)t * 64 + b) * 72 + quad * 8;
    bf16x8 x0 = *(const bf16x8*)xp;
    bf16x8 x1 = *(const bf16x8*)(xp + 32);
    ushort* gdst = gx + ((size_t)t * 64 + b) * 1024 + w * 256 + quad * 4;
#pragma unroll
    for (int j = 0; j < 16; ++j) {
        int g2 = w * 16 + j;
        const ushort* wp = wbf + ((size_t)(g2 * 16 + l16)) * 320 + quad * 8;
        bf16x8 a0 = *(const bf16x8*)wp;
        bf16x8 a1 = *(const bf16x8*)(wp + 32);
        f32x4 A = {0.f, 0.f, 0.f, 0.f};
        A = __builtin_amdgcn_mfma_f32_16x16x32_bf16(a0, x0, A, 0, 0, 0);
        A = __builtin_amdgcn_mfma_f32_16x16x32_bf16(a1, x1, A, 0, 0, 0);
        int u = g2 * 4 + quad;
        uint2 pk;
        pk.x = (uint)f2bf(A[0] + bias[u]) | ((uint)f2bf(A[1] + bias[256 + u]) << 16);
        pk.y = (uint)f2bf(A[2] + bias[512 + u]) | ((uint)f2bf(A[3] + bias[768 + u]) << 16);
        *(uint2*)(gdst + j * 16) = pk;
    }
}

// ---- Kernel 4: SINGLE-CU COMMUNICATION-FREE LSTM scan, v2 (8-wave re-tile).
// R11 post-mortem: 4 waves x 512 regs is impossible — arch VGPR limit is 256/wave
// (other 256 are AGPRs, not addressable by loads/VALU) -> af[16][6]=364 spilled to
// scratch -> 23.7k cy/step scratch-BW-bound. Fix: the SIMD reg FILE is 512 regs either
// way, so 8 waves x 256 VGPR uses all of it natively. Wave w owns 8 M-tiles g2=w*8+j.
// Per-wave W_hh split (64 frags): 40 reg (s=0..4), 18 LDS (s=5,6 all j; s=7 j=0,1),
// 6 streamed from L2 each step (s=7 j=2..7; same addr every step -> L1/L2-hot, issued
// at step top, consumed last -> hidden). LDS: 144 KB weights + 8.4 KB Hs = 152 KB.
// VGPR budget: 160 af + 24 sf + 32 acc + 16 gq + 8 cs + ~14 misc ~= 254 <= 256.
// Everything correctness-bearing (fragment formulas, Hs protocol, epilogue, fill
// swizzle, gx layout) is verbatim from the PASSING R11 kernel.
__global__ __launch_bounds__(512, 2) void k_scan2(const ushort* __restrict__ gx,
                                                  const ushort* __restrict__ wbf,
                                                  float* __restrict__ hfin) {
    __shared__ __align__(16) ushort wlds[144 * 512];  // 147456 B: 144 frag-slots x 1KB
    __shared__ __align__(16) ushort Hs[16 * 264];     // 8448 B: h [b:16][256+8 pad]
    int p = blockIdx.x;
    int tid = threadIdx.x;
    int lane = tid & 63, w = tid >> 6, l16 = lane & 15, quad = lane >> 4;
    int bb = p * 16 + l16;
    // ---- cooperative LDS weight fill: slot = wv*18 + L; L<16 -> (j=L>>1, s=5+(L&1));
    // L>=16 -> (j=L-16, s=7). chunk c of row stored at c^((row>>1)&3) (R11-proven).
    for (int i = tid; i < 144 * 64; i += 512) {
        int slot = i >> 6, ch = i & 63;
        int row = ch >> 2, c = ch & 3, cp = c ^ ((row >> 1) & 3);
        int wv = slot / 18, L = slot - wv * 18;
        int j = (L < 16) ? (L >> 1) : (L - 16);
        int s = (L < 16) ? (5 + (L & 1)) : 7;
        int g2 = wv * 8 + j;
        const ushort* src = wbf + ((size_t)(g2 * 16 + row)) * 320 + (s + 2) * 32 + c * 8;
        *(uint4*)&wlds[slot * 512 + row * 32 + cp * 8] = *(const uint4*)src;
    }
    // ---- stationary reg frags: s=0..4 for all 8 tiles (all indices literal) ----
    bf16x8 af[8][5];
#pragma unroll
    for (int j = 0; j < 8; ++j) {
        const ushort* wp = wbf + ((size_t)((w * 8 + j) * 16 + l16)) * 320 + quad * 8;
#pragma unroll
        for (int s = 0; s < 5; ++s) af[j][s] = *(const bf16x8*)(wp + (s + 2) * 32);
    }
    float cs[8];
#pragma unroll
    for (int j = 0; j < 8; ++j) cs[j] = 0.f;
    const ushort* swbase = wbf + ((size_t)((w * 8 + 2) * 16 + l16)) * 320 + 9 * 32 + quad * 8;
    const int lsw = quad ^ ((l16 >> 1) & 3);  // LDS read chunk (matches fill swizzle)
    const ushort* gxb = gx + (size_t)bb * 1024 + w * 128 + quad * 4;
    __syncthreads();  // wlds fill complete
#pragma unroll 1
    for (int t = 0; t < TC_; ++t) {
        const ushort* gxr = gxb + (size_t)t * 65536;
        // gx gates for all 8 tiles issued at step top (HBM ~900cy, used ~2.3k cy later).
        uint2 gq0[4], gq1[4];
#pragma unroll
        for (int j = 0; j < 4; ++j) gq0[j] = *(const uint2*)(gxr + j * 16);
#pragma unroll
        for (int j = 0; j < 4; ++j) gq1[j] = *(const uint2*)(gxr + 64 + j * 16);
        // stream s=7 frags j=2..7 (L2-hot, same addr every step; consumed at s=7 phase).
        bf16x8 sf[6];
#pragma unroll
        for (int m = 0; m < 6; ++m) sf[m] = *(const bf16x8*)(swbase + (size_t)m * 5120);
        f32x4 A[8];
#pragma unroll
        for (int j = 0; j < 8; ++j) A[j] = (f32x4){0.f, 0.f, 0.f, 0.f};
        if (t > 0) {
            // s=0..4: reg weights.
#pragma unroll
            for (int s = 0; s < 5; ++s) {
                bf16x8 bh = *(const bf16x8*)((const char*)Hs + l16 * 528 + s * 64 + quad * 16);
#pragma unroll
                for (int j = 0; j < 8; ++j)
                    A[j] = __builtin_amdgcn_mfma_f32_16x16x32_bf16(af[j][s], bh, A[j], 0, 0, 0);
            }
            // s=5,6: LDS weights.
#pragma unroll
            for (int s = 5; s < 7; ++s) {
                bf16x8 bh = *(const bf16x8*)((const char*)Hs + l16 * 528 + s * 64 + quad * 16);
#pragma unroll
                for (int j = 0; j < 8; ++j) {
                    bf16x8 a = *(const bf16x8*)&wlds[(w * 18 + j * 2 + (s - 5)) * 512 + l16 * 32 + lsw * 8];
                    A[j] = __builtin_amdgcn_mfma_f32_16x16x32_bf16(a, bh, A[j], 0, 0, 0);
                }
            }
            // s=7: j=0,1 LDS; j=2..7 streamed regs.
            {
                bf16x8 bh = *(const bf16x8*)((const char*)Hs + l16 * 528 + 7 * 64 + quad * 16);
#pragma unroll
                for (int j = 0; j < 2; ++j) {
                    bf16x8 a = *(const bf16x8*)&wlds[(w * 18 + 16 + j) * 512 + l16 * 32 + lsw * 8];
                    A[j] = __builtin_amdgcn_mfma_f32_16x16x32_bf16(a, bh, A[j], 0, 0, 0);
                }
#pragma unroll
                for (int j = 2; j < 8; ++j)
                    A[j] = __builtin_amdgcn_mfma_f32_16x16x32_bf16(sf[j - 2], bh, A[j], 0, 0, 0);
            }
        }
        __syncthreads();  // barrier A: Hs reads of h(t-1) complete before h(t) writes
        bool lastt = (t == TC_ - 1);
#pragma unroll
        for (int j = 0; j < 8; ++j) {
            uint2 g = (j < 4) ? gq0[j] : gq1[j - 4];  // literal select after unroll
            float x0 = __builtin_bit_cast(float, g.x << 16);
            float x1 = __builtin_bit_cast(float, g.x & 0xFFFF0000u);
            float x2 = __builtin_bit_cast(float, g.y << 16);
            float x3 = __builtin_bit_cast(float, g.y & 0xFFFF0000u);
            float gi = A[j][0] + x0, gf = A[j][1] + x1;
            float gg = A[j][2] + x2, go = A[j][3] + x3;
            float ii = sigmoidf_(gi), ff = sigmoidf_(gf), gv = tanhf_(gg), oo = sigmoidf_(go);
            cs[j] = ff * cs[j] + ii * gv;
            float hv = oo * tanhf_(cs[j]);
            int u = w * 32 + j * 4 + quad;
            if (lastt) {
                hfin[u * 64 + bb] = hv;
            } else {
                ushort hb = f2bf(hv);
                uint pr = ((uint)hb) | ((uint)__shfl((int)hb, (lane + 16) & 63) << 16);
                if ((quad & 1) == 0)
                    *(uint*)((char*)Hs + l16 * 528 + u * 2) = pr;  // units u, u+1
            }
        }
        __syncthreads();  // barrier B: h(t) writes visible before next step's reads
    }
}

// ---- Kernel 4-FALLBACK (R8-proven, 2.41ms): used when ws_size can't hold gx. ----
__global__ __launch_bounds__(512) void k_scan(const ushort* __restrict__ li,
                                              const ushort* __restrict__ wbf,
                                              const float* __restrict__ bias,
                                              u64* __restrict__ hbuf,
                                              float* __restrict__ hfin) {
    __shared__ __align__(16) ushort Hs[2][16 * 264];
    int p = blockIdx.x & 7, q = blockIdx.x >> 3;
    if (p >= 4) return;
    int tid = threadIdx.x;
    int lane = tid & 63, wave = tid >> 6, l16 = lane & 15, quad = lane >> 4;
    int bb = p * 16 + l16;
    int g2a = q * 16 + 2 * wave, g2b = g2a + 1;
    int u0 = g2a * 4 + quad, u1 = g2b * 4 + quad;
    int pc = 32 * q + 4 * wave + (quad >> 1);
    bf16x8 af0[10], af1[10];
    const ushort* wp0 = wbf + ((size_t)(g2a * 16 + l16)) * 320 + quad * 8;
    const ushort* wp1 = wbf + ((size_t)(g2b * 16 + l16)) * 320 + quad * 8;
#pragma unroll
    for (int s = 0; s < 10; ++s) { af0[s] = *(const bf16x8*)(wp0 + s * 32);
                                   af1[s] = *(const bf16x8*)(wp1 + s * 32); }
    float bi0 = bias[u0], bf0 = bias[256 + u0], bg0 = bias[512 + u0], bo0 = bias[768 + u0];
    float bi1 = bias[u1], bf1 = bias[256 + u1], bg1 = bias[512 + u1], bo1 = bias[768 + u1];
    float cs0 = 0.f, cs1 = 0.f;
    bool broken = false;
    const ushort* xpp = li + ((size_t)0 * 64 + bb) * 72 + quad * 8;
    bf16x8 x0 = *(const bf16x8*)xpp;
    bf16x8 x1 = *(const bf16x8*)(xpp + 32);
#pragma unroll 1
    for (int t = 0; t < TC_; ++t) {
        f32x4 A0 = {0.f, 0.f, 0.f, 0.f}, A1 = {0.f, 0.f, 0.f, 0.f};
        A0 = __builtin_amdgcn_mfma_f32_16x16x32_bf16(af0[0], x0, A0, 0, 0, 0);
        A1 = __builtin_amdgcn_mfma_f32_16x16x32_bf16(af1[0], x0, A1, 0, 0, 0);
        A0 = __builtin_amdgcn_mfma_f32_16x16x32_bf16(af0[1], x1, A0, 0, 0, 0);
        A1 = __builtin_amdgcn_mfma_f32_16x16x32_bf16(af1[1], x1, A1, 0, 0, 0);
        char* hb = (char*)Hs + (size_t)(t & 1) * (16 * 264 * 2);
        if (t > 0) {
            uint tg = (uint)(t - 1);
            const u64* src = hbuf + ((size_t)((t - 1) & 1) << 13) + p * 2048 + tid * 4;
            u64 vv0, vv1, vv2, vv3;
            bool got = false;
            if (!broken) {
                u32x4 pa, pb;
                bool ok;
                int guard = 0;
                do {
                    asm volatile(
                        "global_load_dwordx4 %0, %2, off sc0\n\t"
                        "global_load_dwordx4 %1, %2, off offset:16 sc0\n\t"
                        "s_waitcnt vmcnt(0)"
                        : "=&v"(pa), "=&v"(pb) : "v"(src) : "memory");
                    uint m = ((pa.x >> 16) ^ tg) | ((pa.y >> 16) ^ tg)
                           | ((pa.z >> 16) ^ tg) | ((pa.w >> 16) ^ tg)
                           | ((pb.x >> 16) ^ tg) | ((pb.y >> 16) ^ tg)
                           | ((pb.z >> 16) ^ tg) | ((pb.w >> 16) ^ tg);
                    ok = (m == 0);
                } while (!__all(ok) && ++guard < 1024);
                got = __all(ok);
                if (got) {
                    vv0 = ((u64)pa.y << 32) | pa.x;
                    vv1 = ((u64)pa.w << 32) | pa.z;
                    vv2 = ((u64)pb.y << 32) | pb.x;
                    vv3 = ((u64)pb.w << 32) | pb.z;
                } else broken = true;
            }
            if (!got) {
                u64 w0, w1, w2, w3;
                bool ok;
                int guard = 0;
                do {
                    w0 = __hip_atomic_load(src + 0, __ATOMIC_RELAXED, __HIP_MEMORY_SCOPE_AGENT);
                    w1 = __hip_atomic_load(src + 1, __ATOMIC_RELAXED, __HIP_MEMORY_SCOPE_AGENT);
                    w2 = __hip_atomic_load(src + 2, __ATOMIC_RELAXED, __HIP_MEMORY_SCOPE_AGENT);
                    w3 = __hip_atomic_load(src + 3, __ATOMIC_RELAXED, __HIP_MEMORY_SCOPE_AGENT);
                    uint m = (((uint)(w0 >> 16) & 0xFFFFu) ^ tg) | (((uint)(w0 >> 48)) ^ tg);
                    m |= (((uint)(w1 >> 16) & 0xFFFFu) ^ tg) | (((uint)(w1 >> 48)) ^ tg);
                    m |= (((uint)(w2 >> 16) & 0xFFFFu) ^ tg) | (((uint)(w2 >> 48)) ^ tg);
                    m |= (((uint)(w3 >> 16) & 0xFFFFu) ^ tg) | (((uint)(w3 >> 48)) ^ tg);
                    ok = (m == 0);
                } while (!__all(ok) && ++guard < (1 << 14));
                vv0 = w0; vv1 = w1; vv2 = w2; vv3 = w3;
            }
            {
                int b = tid >> 5, c0 = (tid * 4) & 127;
                uint4 wv;
                wv.x = ((uint)vv0 & 0xFFFFu) | (((uint)(vv0 >> 32) & 0xFFFFu) << 16);
                wv.y = ((uint)vv1 & 0xFFFFu) | (((uint)(vv1 >> 32) & 0xFFFFu) << 16);
                wv.z = ((uint)vv2 & 0xFFFFu) | (((uint)(vv2 >> 32) & 0xFFFFu) << 16);
                wv.w = ((uint)vv3 & 0xFFFFu) | (((uint)(vv3 >> 32) & 0xFFFFu) << 16);
                *(uint4*)(hb + b * 528 + c0 * 4) = wv;
            }
            __syncthreads();
#pragma unroll
            for (int s = 0; s < 8; ++s) {
                bf16x8 bh = *(const bf16x8*)(hb + l16 * 528 + s * 64 + quad * 16);
                A0 = __builtin_amdgcn_mfma_f32_16x16x32_bf16(af0[2 + s], bh, A0, 0, 0, 0);
                A1 = __builtin_amdgcn_mfma_f32_16x16x32_bf16(af1[2 + s], bh, A1, 0, 0, 0);
            }
        }
        float hv0, hv1;
        {
            float gi = A0[0] + bi0, gf = A0[1] + bf0, gg = A0[2] + bg0, go = A0[3] + bo0;
            float ii = sigmoidf_(gi), ff = sigmoidf_(gf), g2 = tanhf_(gg), oo = sigmoidf_(go);
            cs0 = ff * cs0 + ii * g2;
            hv0 = oo * tanhf_(cs0);
        }
        {
            float gi = A1[0] + bi1, gf = A1[1] + bf1, gg = A1[2] + bg1, go = A1[3] + bo1;
            float ii = sigmoidf_(gi), ff = sigmoidf_(gf), g2 = tanhf_(gg), oo = sigmoidf_(go);
            cs1 = ff * cs1 + ii * g2;
            hv1 = oo * tanhf_(cs1);
        }
        if (t == TC_ - 1) {
            hfin[u0 * 64 + bb] = hv0;
            hfin[u1 * 64 + bb] = hv1;
        } else {
            ushort h0 = f2bf(hv0), h1 = f2bf(hv1);
            uint pr0 = ((uint)h0 & 0xFFFFu) | ((uint)__shfl((int)h0, (lane + 16) & 63) << 16);
            uint pr1 = ((uint)h1 & 0xFFFFu) | ((uint)__shfl((int)h1, (lane + 16) & 63) << 16);
            if ((quad & 1) == 0) {
                uint tg2 = ((uint)t) << 16;
                u64 w0 = (u64)((pr0 & 0xFFFFu) | tg2) | ((u64)((pr0 >> 16) | tg2) << 32);
                u64 w1 = (u64)((pr1 & 0xFFFFu) | tg2) | ((u64)((pr1 >> 16) | tg2) << 32);
                u64* dst = hbuf + ((size_t)(t & 1) << 13) + p * 2048 + l16 * 128;
                __hip_atomic_store(dst + pc, w0, __ATOMIC_RELAXED, __HIP_MEMORY_SCOPE_AGENT);
                __hip_atomic_store(dst + pc + 2, w1, __ATOMIC_RELAXED, __HIP_MEMORY_SCOPE_AGENT);
            }
        }
        int tn = (t + 1 < TC_) ? t + 1 : t;
        const ushort* xpn = li + ((size_t)tn * 64 + bb) * 72 + quad * 8;
        x0 = *(const bf16x8*)xpn;
        x1 = *(const bf16x8*)(xpn + 32);
    }
}

// ---- Kernel 5: out[b][o] = h_final[:,b] . lin_w[o,:] + lin_b[o] ----
__global__ __launch_bounds__(64) void k_fin(const float* __restrict__ hfin, const float* __restrict__ lw,
                                            const float* __restrict__ lb, float* __restrict__ out) {
    int o = blockIdx.x, b = threadIdx.x;
    float acc = lb[o];
    const float* wp = lw + o * 256;
#pragma unroll 4
    for (int u2 = 0; u2 < 256; ++u2) acc += hfin[u2 * 64 + b] * wp[u2];
    out[b * 10 + o] = acc;
}

extern "C" void kernel_launch(void* const* d_in, const int* in_sizes, int n_in,
                              void* d_out, int out_size, void* d_ws, size_t ws_size,
                              hipStream_t stream) {
    const float* in  = (const float*)d_in[0];
    // d_in[1] ("r") unused
    const float* cw  = (const float*)d_in[2];
    const float* cb  = (const float*)d_in[3];
    const float* wih = (const float*)d_in[4];
    const float* whh = (const float*)d_in[5];
    const float* bih = (const float*)d_in[6];
    const float* bhh = (const float*)d_in[7];
    const float* lw  = (const float*)d_in[8];
    const float* lb  = (const float*)d_in[9];
    float* out = (float*)d_out;

    char* ws = (char*)d_ws;
    float*  sq   = (float*)(ws + 0);          // 32768 B
    u64*    hbuf = (u64*)(ws + 32768);        // 131072 B (fallback exchange buffer)
    float*  bias = (float*)(ws + 163840);     // 4096 B
    float*  hfin = (float*)(ws + 167936);     // 65536 B  [u][b] fp32
    ushort* wbf  = (ushort*)(ws + 233472);    // 655360 B [g2][16][320] bf16
    ushort* li   = (ushort*)(ws + 888832);    // 9418752 B [tc][b][72] bf16
    ushort* gx   = (ushort*)(ws + 10307584);  // 133955584 B [tc][b][1024] bf16
    const size_t WS_NEED = 10307584ull + 133955584ull;  // 144,263,168

    hipMemsetAsync(sq, 0, 32768, stream);

    k_sqsum<<<1024, 128, 0, stream>>>(in, sq);
    k_prep<<<1280, 256, 0, stream>>>(wih, whh, bih, bhh, wbf, bias);
    k_conv<<<2048, 256, 0, stream>>>(in, cw, cb, sq, li);
    if (ws_size >= WS_NEED) {
        // Communication-free path: precompute gx, then 4 independent single-CU scans.
        k_gx<<<TC_ * 4, 256, 0, stream>>>(li, wbf, bias, gx);
        k_scan2<<<4, 512, 0, stream>>>(gx, wbf, hfin);
    } else {
        // Fallback: R8-proven pod exchange (2.41 ms).
        hipMemsetAsync(hbuf, 0xFF, 131072, stream);
        k_scan<<<32, 512, 0, stream>>>(li, wbf, bias, hbuf, hfin);
    }
    k_fin<<<10, 64, 0, stream>>>(hfin, lw, lb, out);
}